// Round 13
// baseline (272.142 us; speedup 1.0000x reference)
//
#include <hip/hip_runtime.h>
#include <math.h>

// GAT model: N=50000, E=500000 (+N self loops), D=128, layer1 heads=4.
// Structure: k_init (padded-CSR scatter + weight/const prep, role-split;
// B planes emitted FRAGMENT-MAJOR); k_l1 (rank-1 layer 1, wave/node);
// per layer: k_aggh (edge-softmax aggregate over h -> bf16 hi/lo row-major
// panel; 4-deep float4 gather, proven 43.5us) -> k_gemm (MFMA bf16x3, NO LDS:
// A row-major de-interleave, B frag-major coalesced from L2, fused epilogue).

#define LEAKY(e) ((e) > 0.f ? (e) : 0.2f * (e))

typedef __attribute__((ext_vector_type(8))) short bf16x8;
typedef __attribute__((ext_vector_type(4))) float f32x4;

__device__ inline ushort f32_to_bf16_rne(float f) {
    unsigned u = __float_as_uint(f);
    unsigned r = (u + 0x7FFFu + ((u >> 16) & 1u)) >> 16;
    return (ushort)r;
}
__device__ inline float bf16_to_f32(ushort h) { return __uint_as_float((unsigned)h << 16); }
__device__ inline unsigned pack2(float a, float b) {
    return (unsigned)f32_to_bf16_rne(a) | ((unsigned)f32_to_bf16_rne(b) << 16);
}

// ---------------- Init: scatter (blocks < nScat) + prep (rest) ----------------
// deg has N+1 ints; deg[N] doubles as ovf_cnt.
// consts layout: u[128]@0, v[128]@128, P[4]@256, Q[4]@260, R[4]@264, S[4]@268
// B planes: frag-major wf[((ks*8+nn)*64 + kgrp*16 + lrow)*8 + j]
//   for k = ks*32 + kgrp*8 + j, c = nn*16 + lrow  (verified R9)

__global__ void k_init(const int* __restrict__ ei, int E, int N, int nScat,
                       int* __restrict__ deg, int* __restrict__ csr_pad,
                       int2* __restrict__ ovf, int ovf_cap,
                       const float* __restrict__ Wa, const float* __restrict__ Wb,
                       const float* __restrict__ Wc,
                       const float* __restrict__ asa, const float* __restrict__ asb,
                       const float* __restrict__ asc,
                       const float* __restrict__ ada, const float* __restrict__ adb,
                       const float* __restrict__ adc,
                       const float* __restrict__ W_emb, const float* __restrict__ b_emb,
                       const float* __restrict__ W1g, const float* __restrict__ as1g,
                       const float* __restrict__ ad1g,
                       ushort* __restrict__ hi0, ushort* __restrict__ lo0,
                       ushort* __restrict__ hi1, ushort* __restrict__ lo1,
                       ushort* __restrict__ hi2, ushort* __restrict__ lo2,
                       float* __restrict__ was0, float* __restrict__ was1,
                       float* __restrict__ was2,
                       float* __restrict__ wad0, float* __restrict__ wad1,
                       float* __restrict__ wad2,
                       float* __restrict__ consts) {
    __shared__ float su[128], sv[128];
    int blk = blockIdx.x, tid = threadIdx.x;
    if (blk < nScat) {
        int e = blk * 256 + tid;
        int Et = E + N;
        if (e >= Et) return;
        int src, dst;
        if (e < E) { int2 p = ((const int2*)ei)[e]; src = p.x; dst = p.y; }
        else { src = dst = e - E; }
        int pos = atomicAdd(&deg[dst], 1);
        if (pos < 64) {
            csr_pad[(dst << 6) + pos] = src;
        } else {
            int o = atomicAdd(&deg[N], 1);
            if (o < ovf_cap) ovf[o] = make_int2(dst, src);
        }
        return;
    }
    int b = blk - nScat;     // 0..195
    if (b < 192) {
        int l = b >> 6;
        int idx = (b & 63) * 256 + tid;   // 0..16383
        const float* W = (l == 0) ? Wa : (l == 1) ? Wb : Wc;
        ushort* ph = (l == 0) ? hi0 : (l == 1) ? hi1 : hi2;
        ushort* pl = (l == 0) ? lo0 : (l == 1) ? lo1 : lo2;
        int k = idx >> 7, c = idx & 127;
        float w = W[idx];
        ushort hi = f32_to_bf16_rne(w);
        ushort lo = f32_to_bf16_rne(w - bf16_to_f32(hi));
        int ks = k >> 5, kgrp = (k >> 3) & 3, j = k & 7;
        int nn = c >> 4, lrow = c & 15;
        int off = (((ks * 8 + nn) * 64) + kgrp * 16 + lrow) * 8 + j;
        ph[off] = hi;
        pl[off] = lo;
    } else if (b < 195) {
        if (tid >= 128) return;
        int l = b - 192;
        const float* W  = (l == 0) ? Wa : (l == 1) ? Wb : Wc;
        const float* av = (l == 0) ? asa : (l == 1) ? asb : asc;
        const float* dv = (l == 0) ? ada : (l == 1) ? adb : adc;
        float* ws = (l == 0) ? was0 : (l == 1) ? was1 : was2;
        float* wd = (l == 0) ? wad0 : (l == 1) ? wad1 : wad2;
        int k = tid;
        float s = 0.f, d = 0.f;
        for (int c = 0; c < 128; c++) {
            float w = W[k * 128 + c];
            s += w * av[c];
            d += w * dv[c];
        }
        ws[k] = s; wd[k] = d;
    } else {
        if (tid >= 128) return;
        int f = tid;
        float u = 0.f, v = 0.f;
        for (int k = 0; k < 128; k++) {
            u += W_emb[k] * W1g[k * 128 + f];
            v += b_emb[k] * W1g[k * 128 + f];
        }
        su[f] = u; sv[f] = v;
        consts[f] = u; consts[128 + f] = v;
        __syncthreads();
        if (f < 4) {
            float P = 0.f, Q = 0.f, R = 0.f, S = 0.f;
            for (int j = 0; j < 32; j++) {
                float uu = su[f * 32 + j], vv = sv[f * 32 + j];
                float a = as1g[f * 32 + j], d = ad1g[f * 32 + j];
                P += uu * a; Q += vv * a; R += uu * d; S += vv * d;
            }
            consts[256 + f] = P; consts[260 + f] = Q;
            consts[264 + f] = R; consts[268 + f] = S;
        }
    }
}

// ---------------- Layer 1: one WAVE per node; lane = (edge-lane el, head q) ----
__global__ __launch_bounds__(256) void k_l1(const float* __restrict__ x,
        const int* __restrict__ deg, const int* __restrict__ csr_pad,
        const int2* __restrict__ ovf,
        const float* __restrict__ consts, const float* __restrict__ b1,
        const float* __restrict__ was2, const float* __restrict__ wad2,
        float* __restrict__ hout, float* __restrict__ a_s, float* __restrict__ a_d,
        int n) {
    int w = threadIdx.x >> 6, lane = threadIdx.x & 63;
    int node = blockIdx.x * 4 + w;
    if (node >= n) return;
    int q = lane & 3;        // head
    int el = lane >> 2;      // edge lane 0..15
    float P = consts[256 + q], Q = consts[260 + q];
    float R = consts[264 + q], Sc = consts[268 + q];
    float xd = x[node];
    float c0 = xd * R + Sc + Q;          // e = leaky(xs*P + c0)
    int dg = deg[node];
    int dlim = min(dg, 64);
    float den = 0.f, S = 0.f;
    for (int i = el; i < dlim; i += 16) {
        float xs = x[csr_pad[(node << 6) + i]];
        float e = xs * P + c0;
        e = LEAKY(e);
        float wgt = __expf(e);
        den += wgt;
        S += wgt * xs;
    }
    if (dg > 64) {
        int no = deg[n];     // ovf count stored at deg[N]
        for (int i = el; i < no; i += 16) {
            int2 p = ovf[i];
            if (p.x == node) {
                float xs = x[p.y];
                float e = xs * P + c0;
                e = LEAKY(e);
                float wgt = __expf(e);
                den += wgt;
                S += wgt * xs;
            }
        }
    }
#pragma unroll
    for (int off = 4; off < 64; off <<= 1) {
        den += __shfl_xor(den, off, 64);
        S += __shfl_xor(S, off, 64);
    }
    float inv = 1.f / (den + 1e-16f);
    float Sn = S * inv, Swn = den * inv;
    int f = q * 32 + el * 2;
    float2 u  = *(const float2*)(consts + f);
    float2 v  = *(const float2*)(consts + 128 + f);
    float2 bb = *(const float2*)(b1 + f);
    float2 ws = *(const float2*)(was2 + f);
    float2 wd = *(const float2*)(wad2 + f);
    float v0 = fmaxf(Sn * u.x + Swn * v.x + bb.x, 0.f);
    float v1 = fmaxf(Sn * u.y + Swn * v.y + bb.y, 0.f);
    *(float2*)(hout + (size_t)node * 128 + f) = make_float2(v0, v1);
    float ps = v0 * ws.x + v1 * ws.y;
    float pd = v0 * wd.x + v1 * wd.y;
#pragma unroll
    for (int off = 1; off < 64; off <<= 1) {
        ps += __shfl_xor(ps, off, 64);
        pd += __shfl_xor(pd, off, 64);
    }
    if (lane == 0) { a_s[node] = ps; a_d[node] = pd; }
}

// ---------------- Aggregation over h (f32), output packed bf16 hi/lo ----------------
// One wave per dst node. Fast path: float4 gather, two edges/iteration
// (lanes 0-31 -> edge j, lanes 32-63 -> edge j+1); LDS zero-padded, no tail.
// (4-deep load pipeline: the measured optimum; 8-deep cost occupancy, R12.)
__global__ __launch_bounds__(256) void k_aggh(const float* __restrict__ h,
        const float* __restrict__ as, const float* __restrict__ ad,
        const int* __restrict__ deg, const int* __restrict__ csr_pad,
        const int2* __restrict__ ovf,
        unsigned* __restrict__ aggp, int n) {
    __shared__ int2 s_sw[4][64];
    int w = threadIdx.x >> 6, lane = threadIdx.x & 63;
    int node = blockIdx.x * 4 + w;
    if (node >= n) return;
    int dg = deg[node];
    float adval = ad[node];
    const char* hbase = (const char*)h;

    if (dg <= 64) {
        int boff = 0;
        float e = -INFINITY;
        if (lane < dg) {
            int src = csr_pad[(node << 6) + lane];
            boff = src << 9;                  // src * 512 bytes
            e = LEAKY(as[src] + adval);
        }
        float m = e;
#pragma unroll
        for (int off = 32; off > 0; off >>= 1) m = fmaxf(m, __shfl_xor(m, off, 64));
        float wt = (lane < dg) ? __expf(e - m) : 0.f;
        float den = wt;
#pragma unroll
        for (int off = 32; off > 0; off >>= 1) den += __shfl_xor(den, off, 64);
        s_sw[w][lane] = make_int2(boff, __float_as_int(wt));   // zero-padded beyond deg
        __builtin_amdgcn_wave_barrier();

        int half = lane >> 5;          // which edge of the pair
        int q16 = (lane & 31) * 16;    // byte offset of this lane's feature quad
        float4 acc = make_float4(0.f, 0.f, 0.f, 0.f);
        int degp = (dg + 7) & ~7;
        for (int j = 0; j < degp; j += 8) {
#pragma unroll
            for (int t = 0; t < 4; t++) {
                int2 p = s_sw[w][j + 2 * t + half];
                float4 v = *(const float4*)(hbase + p.x + q16);
                float wt2 = __int_as_float(p.y);
                acc.x += wt2 * v.x; acc.y += wt2 * v.y;
                acc.z += wt2 * v.z; acc.w += wt2 * v.w;
            }
        }
        acc.x += __shfl_xor(acc.x, 32, 64);
        acc.y += __shfl_xor(acc.y, 32, 64);
        acc.z += __shfl_xor(acc.z, 32, 64);
        acc.w += __shfl_xor(acc.w, 32, 64);
        float inv = 1.f / (den + 1e-16f);
        if (lane < 32) {
            float o0 = acc.x * inv, o1 = acc.y * inv;
            float o2 = acc.z * inv, o3 = acc.w * inv;
            ushort h0 = f32_to_bf16_rne(o0), h1 = f32_to_bf16_rne(o1);
            ushort h2 = f32_to_bf16_rne(o2), h3 = f32_to_bf16_rne(o3);
            uint4 pk;
            pk.x = (unsigned)h0 | ((unsigned)h1 << 16);
            pk.y = pack2(o0 - bf16_to_f32(h0), o1 - bf16_to_f32(h1));
            pk.z = (unsigned)h2 | ((unsigned)h3 << 16);
            pk.w = pack2(o2 - bf16_to_f32(h2), o3 - bf16_to_f32(h3));
            ((uint4*)aggp)[(size_t)node * 32 + lane] = pk;
        }
    } else {
        // deg > 64: 64 padded edges + overflow list scan (rare/never on this graph)
        int lane8 = lane * 8;
        int no = deg[n];
        int psrc = csr_pad[(node << 6) + lane];   // all 64 slots full
        float m = LEAKY(as[psrc] + adval);
        for (int i = lane; i < no; i += 64) {
            int2 p = ovf[i];
            if (p.x == node) m = fmaxf(m, LEAKY(as[p.y] + adval));
        }
#pragma unroll
        for (int off = 32; off > 0; off >>= 1) m = fmaxf(m, __shfl_xor(m, off, 64));
        float den = 0.f;
        float2 acc = make_float2(0.f, 0.f);
        for (int i = 0; i < 64; i++) {
            int src = csr_pad[(node << 6) + i];
            float e = LEAKY(as[src] + adval);
            float wt = __expf(e - m);
            den += wt;
            float2 v = *(const float2*)(hbase + ((size_t)src << 9) + lane8);
            acc.x += wt * v.x; acc.y += wt * v.y;
        }
        for (int i = 0; i < no; i++) {
            int2 p = ovf[i];
            if (p.x == node) {
                float e = LEAKY(as[p.y] + adval);
                float wt = __expf(e - m);
                den += wt;
                float2 v = *(const float2*)(hbase + ((size_t)p.y << 9) + lane8);
                acc.x += wt * v.x; acc.y += wt * v.y;
            }
        }
        float inv = 1.f / (den + 1e-16f);
        float o0 = acc.x * inv, o1 = acc.y * inv;
        ushort h0 = f32_to_bf16_rne(o0), h1 = f32_to_bf16_rne(o1);
        ((uint2*)aggp)[(size_t)node * 64 + lane] =
            make_uint2((unsigned)h0 | ((unsigned)h1 << 16),
                       pack2(o0 - bf16_to_f32(h0), o1 - bf16_to_f32(h1)));
    }
}

// ---------------- MFMA GEMM, NO LDS, no barrier ----------------
// 256 threads = 4 waves; block = 64 rows; wave = 16 rows x 128 cols; K=128.
// A: row-major aggp, uint4 de-interleave (R11-proven). B: frag-major from L2,
// 16 B/lane perfectly coalesced. Fused bias/relu/hout/next-alpha epilogue.
__global__ __launch_bounds__(256) void k_gemm(const uint2* __restrict__ aggp,
        const ushort* __restrict__ wf_hi, const ushort* __restrict__ wf_lo,
        const float* __restrict__ bias, float* __restrict__ hout,
        const float* __restrict__ was_nx, const float* __restrict__ wad_nx,
        float* __restrict__ as_nx, float* __restrict__ ad_nx,
        int n, int do_relu) {
    int tid = threadIdx.x, wid = tid >> 6, lane = tid & 63;
    int lrow = lane & 15, kgrp = lane >> 4;
    int row_base = blockIdx.x * 64 + wid * 16;
    int arow = min(row_base + lrow, n - 1);
    const uint4* ap = (const uint4*)(aggp + (size_t)arow * 64);

    float bv[8], wsv[8], wdv[8];
#pragma unroll
    for (int nn = 0; nn < 8; nn++) bv[nn] = bias[nn * 16 + lrow];
    if (was_nx) {
#pragma unroll
        for (int nn = 0; nn < 8; nn++) {
            wsv[nn] = was_nx[nn * 16 + lrow];
            wdv[nn] = wad_nx[nn * 16 + lrow];
        }
    }

    f32x4 acc[8];
#pragma unroll
    for (int nn = 0; nn < 8; nn++) { acc[nn][0] = 0.f; acc[nn][1] = 0.f; acc[nn][2] = 0.f; acc[nn][3] = 0.f; }

#pragma unroll
    for (int ks = 0; ks < 4; ks++) {
        uint4 q0 = ap[ks * 8 + kgrp * 2];
        uint4 q1 = ap[ks * 8 + kgrp * 2 + 1];
        int4 hi4 = make_int4(q0.x, q0.z, q1.x, q1.z);
        int4 lo4 = make_int4(q0.y, q0.w, q1.y, q1.w);
        bf16x8 ah = *(bf16x8*)&hi4;
        bf16x8 al = *(bf16x8*)&lo4;
#pragma unroll
        for (int nn = 0; nn < 8; nn++) {
            size_t boff = ((size_t)(ks * 8 + nn) * 64 + lane) * 8;
            bf16x8 bh = *(const bf16x8*)(wf_hi + boff);
            bf16x8 bl = *(const bf16x8*)(wf_lo + boff);
            acc[nn] = __builtin_amdgcn_mfma_f32_16x16x32_bf16(ah, bh, acc[nn], 0, 0, 0);
            acc[nn] = __builtin_amdgcn_mfma_f32_16x16x32_bf16(ah, bl, acc[nn], 0, 0, 0);
            acc[nn] = __builtin_amdgcn_mfma_f32_16x16x32_bf16(al, bh, acc[nn], 0, 0, 0);
        }
    }

#pragma unroll
    for (int i = 0; i < 4; i++) {
        int row = row_base + kgrp * 4 + i;
        if (row < n) {
            float ps = 0.f, pd = 0.f;
#pragma unroll
            for (int nn = 0; nn < 8; nn++) {
                float val = acc[nn][i] + bv[nn];
                if (do_relu) val = fmaxf(val, 0.f);
                hout[(size_t)row * 128 + nn * 16 + lrow] = val;
                if (was_nx) { ps += val * wsv[nn]; pd += val * wdv[nn]; }
            }
            if (was_nx) {
#pragma unroll
                for (int off = 1; off < 16; off <<= 1) {
                    ps += __shfl_xor(ps, off, 16);
                    pd += __shfl_xor(pd, off, 16);
                }
                if (lrow == 0) { as_nx[row] = ps; ad_nx[row] = pd; }
            }
        }
    }
}

// ---------------- launch ----------------

extern "C" void kernel_launch(void* const* d_in, const int* in_sizes, int n_in,
                              void* d_out, int out_size, void* d_ws, size_t ws_size,
                              hipStream_t stream) {
    const float* x     = (const float*)d_in[0];
    const int*   ei    = (const int*)d_in[1];
    const float* W_emb = (const float*)d_in[2];
    const float* b_emb = (const float*)d_in[3];
    const float* W1g   = (const float*)d_in[4];
    const float* as1g  = (const float*)d_in[5];
    const float* ad1g  = (const float*)d_in[6];
    const float* b1    = (const float*)d_in[7];
    const float* Wl[3]  = {(const float*)d_in[8],  (const float*)d_in[12], (const float*)d_in[16]};
    const float* asl[3] = {(const float*)d_in[9],  (const float*)d_in[13], (const float*)d_in[17]};
    const float* adl[3] = {(const float*)d_in[10], (const float*)d_in[14], (const float*)d_in[18]};
    const float* bl[3]  = {(const float*)d_in[11], (const float*)d_in[15], (const float*)d_in[19]};
    float* out = (float*)d_out;

    int N = in_sizes[0];
    int E = in_sizes[1] / 2;
    int Et = E + N;
    const int OVF_CAP = 65536;
    int nScat = (Et + 255) / 256;

    char* ws = (char*)d_ws;
    size_t off = 0;
    auto alloc = [&](size_t bytes) { size_t p = off; off += (bytes + 255) & ~(size_t)255; return p; };
    int*   deg      = (int*)(ws + alloc((size_t)(N + 1) * 4));   // deg[N] = ovf count
    int2*  ovf      = (int2*)(ws + alloc((size_t)OVF_CAP * 8));
    int*   csr_pad  = (int*)(ws + alloc((size_t)N * 64 * 4));
    float* consts   = (float*)(ws + alloc(272 * 4));
    float* a_s0     = (float*)(ws + alloc((size_t)N * 4));
    float* a_d0     = (float*)(ws + alloc((size_t)N * 4));
    float* a_s1     = (float*)(ws + alloc((size_t)N * 4));
    float* a_d1     = (float*)(ws + alloc((size_t)N * 4));
    float* hA       = (float*)(ws + alloc((size_t)N * 128 * 4));
    unsigned* aggp  = (unsigned*)(ws + alloc((size_t)N * 64 * 8));
    ushort* wf_hi[3]; ushort* wf_lo[3];
    float* was[3]; float* wad[3];
    for (int l = 0; l < 3; l++) {
        wf_hi[l] = (ushort*)(ws + alloc(128 * 128 * 2));
        wf_lo[l] = (ushort*)(ws + alloc(128 * 128 * 2));
        was[l]   = (float*)(ws + alloc(128 * 4));
        wad[l]   = (float*)(ws + alloc(128 * 4));
    }

    hipMemsetAsync(deg, 0, (size_t)(N + 1) * 4, stream);
    k_init<<<nScat + 196, 256, 0, stream>>>(ei, E, N, nScat, deg, csr_pad, ovf, OVF_CAP,
                                            Wl[0], Wl[1], Wl[2], asl[0], asl[1], asl[2],
                                            adl[0], adl[1], adl[2],
                                            W_emb, b_emb, W1g, as1g, ad1g,
                                            wf_hi[0], wf_lo[0], wf_hi[1], wf_lo[1],
                                            wf_hi[2], wf_lo[2],
                                            was[0], was[1], was[2], wad[0], wad[1], wad[2],
                                            consts);

    k_l1<<<(N + 3) / 4, 256, 0, stream>>>(x, deg, csr_pad, ovf, consts, b1,
                                          was[0], wad[0], hA, a_s0, a_d0, N);

    float* as_cur = a_s0; float* ad_cur = a_d0;
    float* as_nxt = a_s1; float* ad_nxt = a_d1;
    for (int l = 0; l < 3; l++) {
        k_aggh<<<(N + 3) / 4, 256, 0, stream>>>(hA, as_cur, ad_cur, deg, csr_pad,
                                                ovf, aggp, N);
        if (l < 2) {
            k_gemm<<<(N + 63) / 64, 256, 0, stream>>>((const uint2*)aggp, wf_hi[l], wf_lo[l], bl[l], hA,
                                                      was[l + 1], wad[l + 1], as_nxt, ad_nxt, N, 1);
            float* t;
            t = as_cur; as_cur = as_nxt; as_nxt = t;
            t = ad_cur; ad_cur = ad_nxt; ad_nxt = t;
        } else {
            k_gemm<<<(N + 63) / 64, 256, 0, stream>>>((const uint2*)aggp, wf_hi[l], wf_lo[l], bl[l], out,
                                                      nullptr, nullptr, nullptr, nullptr, N, 0);
        }
    }
}

// Round 14
// 242.906 us; speedup vs baseline: 1.1204x; 1.1204x over previous
//
#include <hip/hip_runtime.h>
#include <math.h>

// GAT model: N=50000, E=500000 (+N self loops), D=128, layer1 heads=4.
// BEST MEASURED CONFIG (R11, 247.4us) — exact revert.
// Structure: k_init (padded-CSR scatter + weight/const prep, role-split);
// k_l1 (rank-1 layer 1, wave/node); per layer: k_aggh (edge-softmax aggregate
// over h -> bf16 hi/lo panel, 4-deep float4 gather) -> k_gemm (MFMA bf16x3,
// B in LDS, A preloaded, fused bias/relu/alpha epilogue).

#define LEAKY(e) ((e) > 0.f ? (e) : 0.2f * (e))

typedef __attribute__((ext_vector_type(8))) short bf16x8;
typedef __attribute__((ext_vector_type(4))) float f32x4;

__device__ inline ushort f32_to_bf16_rne(float f) {
    unsigned u = __float_as_uint(f);
    unsigned r = (u + 0x7FFFu + ((u >> 16) & 1u)) >> 16;
    return (ushort)r;
}
__device__ inline float bf16_to_f32(ushort h) { return __uint_as_float((unsigned)h << 16); }
__device__ inline unsigned pack2(float a, float b) {
    return (unsigned)f32_to_bf16_rne(a) | ((unsigned)f32_to_bf16_rne(b) << 16);
}

// ---------------- Init: scatter (blocks < nScat) + prep (rest) ----------------
// deg has N+1 ints; deg[N] doubles as ovf_cnt.
// consts layout: u[128]@0, v[128]@128, P[4]@256, Q[4]@260, R[4]@264, S[4]@268

__global__ void k_init(const int* __restrict__ ei, int E, int N, int nScat,
                       int* __restrict__ deg, int* __restrict__ csr_pad,
                       int2* __restrict__ ovf, int ovf_cap,
                       const float* __restrict__ Wa, const float* __restrict__ Wb,
                       const float* __restrict__ Wc,
                       const float* __restrict__ asa, const float* __restrict__ asb,
                       const float* __restrict__ asc,
                       const float* __restrict__ ada, const float* __restrict__ adb,
                       const float* __restrict__ adc,
                       const float* __restrict__ W_emb, const float* __restrict__ b_emb,
                       const float* __restrict__ W1g, const float* __restrict__ as1g,
                       const float* __restrict__ ad1g,
                       ushort* __restrict__ hi0, ushort* __restrict__ lo0,
                       ushort* __restrict__ hi1, ushort* __restrict__ lo1,
                       ushort* __restrict__ hi2, ushort* __restrict__ lo2,
                       float* __restrict__ was0, float* __restrict__ was1,
                       float* __restrict__ was2,
                       float* __restrict__ wad0, float* __restrict__ wad1,
                       float* __restrict__ wad2,
                       float* __restrict__ consts) {
    __shared__ float su[128], sv[128];
    int blk = blockIdx.x, tid = threadIdx.x;
    if (blk < nScat) {
        int e = blk * 256 + tid;
        int Et = E + N;
        if (e >= Et) return;
        int src, dst;
        if (e < E) { int2 p = ((const int2*)ei)[e]; src = p.x; dst = p.y; }
        else { src = dst = e - E; }
        int pos = atomicAdd(&deg[dst], 1);
        if (pos < 64) {
            csr_pad[(dst << 6) + pos] = src;
        } else {
            int o = atomicAdd(&deg[N], 1);
            if (o < ovf_cap) ovf[o] = make_int2(dst, src);
        }
        return;
    }
    int b = blk - nScat;     // 0..195
    if (b < 192) {
        int l = b >> 6;
        int idx = (b & 63) * 256 + tid;   // 0..16383
        const float* W = (l == 0) ? Wa : (l == 1) ? Wb : Wc;
        ushort* ph = (l == 0) ? hi0 : (l == 1) ? hi1 : hi2;
        ushort* pl = (l == 0) ? lo0 : (l == 1) ? lo1 : lo2;
        int k = idx >> 7, c = idx & 127;
        float w = W[idx];
        ushort hi = f32_to_bf16_rne(w);
        ushort lo = f32_to_bf16_rne(w - bf16_to_f32(hi));
        ph[c * 128 + k] = hi;     // transposed: [col][k]
        pl[c * 128 + k] = lo;
    } else if (b < 195) {
        if (tid >= 128) return;
        int l = b - 192;
        const float* W  = (l == 0) ? Wa : (l == 1) ? Wb : Wc;
        const float* av = (l == 0) ? asa : (l == 1) ? asb : asc;
        const float* dv = (l == 0) ? ada : (l == 1) ? adb : adc;
        float* ws = (l == 0) ? was0 : (l == 1) ? was1 : was2;
        float* wd = (l == 0) ? wad0 : (l == 1) ? wad1 : wad2;
        int k = tid;
        float s = 0.f, d = 0.f;
        for (int c = 0; c < 128; c++) {
            float w = W[k * 128 + c];
            s += w * av[c];
            d += w * dv[c];
        }
        ws[k] = s; wd[k] = d;
    } else {
        if (tid >= 128) return;
        int f = tid;
        float u = 0.f, v = 0.f;
        for (int k = 0; k < 128; k++) {
            u += W_emb[k] * W1g[k * 128 + f];
            v += b_emb[k] * W1g[k * 128 + f];
        }
        su[f] = u; sv[f] = v;
        consts[f] = u; consts[128 + f] = v;
        __syncthreads();
        if (f < 4) {
            float P = 0.f, Q = 0.f, R = 0.f, S = 0.f;
            for (int j = 0; j < 32; j++) {
                float uu = su[f * 32 + j], vv = sv[f * 32 + j];
                float a = as1g[f * 32 + j], d = ad1g[f * 32 + j];
                P += uu * a; Q += vv * a; R += uu * d; S += vv * d;
            }
            consts[256 + f] = P; consts[260 + f] = Q;
            consts[264 + f] = R; consts[268 + f] = S;
        }
    }
}

// ---------------- Layer 1: one WAVE per node; lane = (edge-lane el, head q) ----
__global__ __launch_bounds__(256) void k_l1(const float* __restrict__ x,
        const int* __restrict__ deg, const int* __restrict__ csr_pad,
        const int2* __restrict__ ovf,
        const float* __restrict__ consts, const float* __restrict__ b1,
        const float* __restrict__ was2, const float* __restrict__ wad2,
        float* __restrict__ hout, float* __restrict__ a_s, float* __restrict__ a_d,
        int n) {
    int w = threadIdx.x >> 6, lane = threadIdx.x & 63;
    int node = blockIdx.x * 4 + w;
    if (node >= n) return;
    int q = lane & 3;        // head
    int el = lane >> 2;      // edge lane 0..15
    float P = consts[256 + q], Q = consts[260 + q];
    float R = consts[264 + q], Sc = consts[268 + q];
    float xd = x[node];
    float c0 = xd * R + Sc + Q;          // e = leaky(xs*P + c0)
    int dg = deg[node];
    int dlim = min(dg, 64);
    float den = 0.f, S = 0.f;
    for (int i = el; i < dlim; i += 16) {
        float xs = x[csr_pad[(node << 6) + i]];
        float e = xs * P + c0;
        e = LEAKY(e);
        float wgt = __expf(e);
        den += wgt;
        S += wgt * xs;
    }
    if (dg > 64) {
        int no = deg[n];     // ovf count stored at deg[N]
        for (int i = el; i < no; i += 16) {
            int2 p = ovf[i];
            if (p.x == node) {
                float xs = x[p.y];
                float e = xs * P + c0;
                e = LEAKY(e);
                float wgt = __expf(e);
                den += wgt;
                S += wgt * xs;
            }
        }
    }
#pragma unroll
    for (int off = 4; off < 64; off <<= 1) {
        den += __shfl_xor(den, off, 64);
        S += __shfl_xor(S, off, 64);
    }
    float inv = 1.f / (den + 1e-16f);
    float Sn = S * inv, Swn = den * inv;
    int f = q * 32 + el * 2;
    float2 u  = *(const float2*)(consts + f);
    float2 v  = *(const float2*)(consts + 128 + f);
    float2 bb = *(const float2*)(b1 + f);
    float2 ws = *(const float2*)(was2 + f);
    float2 wd = *(const float2*)(wad2 + f);
    float v0 = fmaxf(Sn * u.x + Swn * v.x + bb.x, 0.f);
    float v1 = fmaxf(Sn * u.y + Swn * v.y + bb.y, 0.f);
    *(float2*)(hout + (size_t)node * 128 + f) = make_float2(v0, v1);
    float ps = v0 * ws.x + v1 * ws.y;
    float pd = v0 * wd.x + v1 * wd.y;
#pragma unroll
    for (int off = 1; off < 64; off <<= 1) {
        ps += __shfl_xor(ps, off, 64);
        pd += __shfl_xor(pd, off, 64);
    }
    if (lane == 0) { a_s[node] = ps; a_d[node] = pd; }
}

// ---------------- Aggregation over h (f32), output packed bf16 hi/lo ----------------
// One wave per dst node. Fast path: float4 gather, two edges/iteration
// (lanes 0-31 -> edge j, lanes 32-63 -> edge j+1); LDS zero-padded, no tail.
__global__ __launch_bounds__(256) void k_aggh(const float* __restrict__ h,
        const float* __restrict__ as, const float* __restrict__ ad,
        const int* __restrict__ deg, const int* __restrict__ csr_pad,
        const int2* __restrict__ ovf,
        unsigned* __restrict__ aggp, int n) {
    __shared__ int2 s_sw[4][64];
    int w = threadIdx.x >> 6, lane = threadIdx.x & 63;
    int node = blockIdx.x * 4 + w;
    if (node >= n) return;
    int dg = deg[node];
    float adval = ad[node];
    const char* hbase = (const char*)h;

    if (dg <= 64) {
        int boff = 0;
        float e = -INFINITY;
        if (lane < dg) {
            int src = csr_pad[(node << 6) + lane];
            boff = src << 9;                  // src * 512 bytes
            e = LEAKY(as[src] + adval);
        }
        float m = e;
#pragma unroll
        for (int off = 32; off > 0; off >>= 1) m = fmaxf(m, __shfl_xor(m, off, 64));
        float wt = (lane < dg) ? __expf(e - m) : 0.f;
        float den = wt;
#pragma unroll
        for (int off = 32; off > 0; off >>= 1) den += __shfl_xor(den, off, 64);
        s_sw[w][lane] = make_int2(boff, __float_as_int(wt));   // zero-padded beyond deg
        __builtin_amdgcn_wave_barrier();

        int half = lane >> 5;          // which edge of the pair
        int q16 = (lane & 31) * 16;    // byte offset of this lane's feature quad
        float4 acc = make_float4(0.f, 0.f, 0.f, 0.f);
        int degp = (dg + 7) & ~7;
        for (int j = 0; j < degp; j += 8) {
#pragma unroll
            for (int t = 0; t < 4; t++) {
                int2 p = s_sw[w][j + 2 * t + half];
                float4 v = *(const float4*)(hbase + p.x + q16);
                float wt2 = __int_as_float(p.y);
                acc.x += wt2 * v.x; acc.y += wt2 * v.y;
                acc.z += wt2 * v.z; acc.w += wt2 * v.w;
            }
        }
        acc.x += __shfl_xor(acc.x, 32, 64);
        acc.y += __shfl_xor(acc.y, 32, 64);
        acc.z += __shfl_xor(acc.z, 32, 64);
        acc.w += __shfl_xor(acc.w, 32, 64);
        float inv = 1.f / (den + 1e-16f);
        if (lane < 32) {
            float o0 = acc.x * inv, o1 = acc.y * inv;
            float o2 = acc.z * inv, o3 = acc.w * inv;
            ushort h0 = f32_to_bf16_rne(o0), h1 = f32_to_bf16_rne(o1);
            ushort h2 = f32_to_bf16_rne(o2), h3 = f32_to_bf16_rne(o3);
            uint4 pk;
            pk.x = (unsigned)h0 | ((unsigned)h1 << 16);
            pk.y = pack2(o0 - bf16_to_f32(h0), o1 - bf16_to_f32(h1));
            pk.z = (unsigned)h2 | ((unsigned)h3 << 16);
            pk.w = pack2(o2 - bf16_to_f32(h2), o3 - bf16_to_f32(h3));
            ((uint4*)aggp)[(size_t)node * 32 + lane] = pk;
        }
    } else {
        // deg > 64: 64 padded edges + overflow list scan (rare/never on this graph)
        int lane8 = lane * 8;
        int no = deg[n];
        int psrc = csr_pad[(node << 6) + lane];   // all 64 slots full
        float m = LEAKY(as[psrc] + adval);
        for (int i = lane; i < no; i += 64) {
            int2 p = ovf[i];
            if (p.x == node) m = fmaxf(m, LEAKY(as[p.y] + adval));
        }
#pragma unroll
        for (int off = 32; off > 0; off >>= 1) m = fmaxf(m, __shfl_xor(m, off, 64));
        float den = 0.f;
        float2 acc = make_float2(0.f, 0.f);
        for (int i = 0; i < 64; i++) {
            int src = csr_pad[(node << 6) + i];
            float e = LEAKY(as[src] + adval);
            float wt = __expf(e - m);
            den += wt;
            float2 v = *(const float2*)(hbase + ((size_t)src << 9) + lane8);
            acc.x += wt * v.x; acc.y += wt * v.y;
        }
        for (int i = 0; i < no; i++) {
            int2 p = ovf[i];
            if (p.x == node) {
                float e = LEAKY(as[p.y] + adval);
                float wt = __expf(e - m);
                den += wt;
                float2 v = *(const float2*)(hbase + ((size_t)p.y << 9) + lane8);
                acc.x += wt * v.x; acc.y += wt * v.y;
            }
        }
        float inv = 1.f / (den + 1e-16f);
        float o0 = acc.x * inv, o1 = acc.y * inv;
        ushort h0 = f32_to_bf16_rne(o0), h1 = f32_to_bf16_rne(o1);
        ((uint2*)aggp)[(size_t)node * 64 + lane] =
            make_uint2((unsigned)h0 | ((unsigned)h1 << 16),
                       pack2(o0 - bf16_to_f32(h0), o1 - bf16_to_f32(h1)));
    }
}

// ---------------- MFMA GEMM + fused epilogue, B in LDS, A preloaded ----------------
__global__ __launch_bounds__(512) void k_gemm(const uint2* __restrict__ aggp,
        const ushort* __restrict__ wt_hi, const ushort* __restrict__ wt_lo,
        const float* __restrict__ bias, float* __restrict__ hout,
        const float* __restrict__ was_nx, const float* __restrict__ wad_nx,
        float* __restrict__ as_nx, float* __restrict__ ad_nx,
        int n, int do_relu) {
    __shared__ ushort Bh[16 * 128 * 8];   // 32 KB
    __shared__ ushort Bl[16 * 128 * 8];   // 32 KB
    int tid = threadIdx.x;
#pragma unroll
    for (int rep = 0; rep < 4; rep++) {
        int c = rep * 512 + tid;          // 0..2047
        int col = c >> 4, kc = c & 15;
        *(uint4*)(Bh + (size_t)(kc * 128 + col) * 8) = *(const uint4*)(wt_hi + (size_t)col * 128 + kc * 8);
        *(uint4*)(Bl + (size_t)(kc * 128 + col) * 8) = *(const uint4*)(wt_lo + (size_t)col * 128 + kc * 8);
    }

    int wid = tid >> 6, lane = tid & 63;
    int lrow = lane & 15, kgrp = lane >> 4;
    int row_base = blockIdx.x * 128 + wid * 16;
    int arow = min(row_base + lrow, n - 1);

    // preload entire A panel + epilogue vectors before the barrier
    const uint4* ap = (const uint4*)(aggp + (size_t)arow * 64);
    uint4 qa[8];
#pragma unroll
    for (int ks = 0; ks < 4; ks++) {
        qa[2 * ks]     = ap[ks * 8 + kgrp * 2];
        qa[2 * ks + 1] = ap[ks * 8 + kgrp * 2 + 1];
    }
    float bv[8], wsv[8], wdv[8];
#pragma unroll
    for (int nn = 0; nn < 8; nn++) bv[nn] = bias[nn * 16 + lrow];
    if (was_nx) {
#pragma unroll
        for (int nn = 0; nn < 8; nn++) {
            wsv[nn] = was_nx[nn * 16 + lrow];
            wdv[nn] = wad_nx[nn * 16 + lrow];
        }
    }
    __syncthreads();

    f32x4 acc[8];
#pragma unroll
    for (int nn = 0; nn < 8; nn++) { acc[nn][0] = 0.f; acc[nn][1] = 0.f; acc[nn][2] = 0.f; acc[nn][3] = 0.f; }

#pragma unroll
    for (int ks = 0; ks < 4; ks++) {
        uint4 q0 = qa[2 * ks], q1 = qa[2 * ks + 1];
        int4 hi4 = make_int4(q0.x, q0.z, q1.x, q1.z);
        int4 lo4 = make_int4(q0.y, q0.w, q1.y, q1.w);
        bf16x8 ah = *(bf16x8*)&hi4;
        bf16x8 al = *(bf16x8*)&lo4;
        int kc = ks * 4 + kgrp;
#pragma unroll
        for (int nn = 0; nn < 8; nn++) {
            int col = nn * 16 + lrow;
            bf16x8 bh = *(const bf16x8*)(Bh + (size_t)(kc * 128 + col) * 8);
            bf16x8 bl = *(const bf16x8*)(Bl + (size_t)(kc * 128 + col) * 8);
            acc[nn] = __builtin_amdgcn_mfma_f32_16x16x32_bf16(ah, bh, acc[nn], 0, 0, 0);
            acc[nn] = __builtin_amdgcn_mfma_f32_16x16x32_bf16(ah, bl, acc[nn], 0, 0, 0);
            acc[nn] = __builtin_amdgcn_mfma_f32_16x16x32_bf16(al, bh, acc[nn], 0, 0, 0);
        }
    }

#pragma unroll
    for (int i = 0; i < 4; i++) {
        int row = row_base + kgrp * 4 + i;
        if (row < n) {
            float ps = 0.f, pd = 0.f;
#pragma unroll
            for (int nn = 0; nn < 8; nn++) {
                float val = acc[nn][i] + bv[nn];
                if (do_relu) val = fmaxf(val, 0.f);
                hout[(size_t)row * 128 + nn * 16 + lrow] = val;
                if (was_nx) { ps += val * wsv[nn]; pd += val * wdv[nn]; }
            }
            if (was_nx) {
#pragma unroll
                for (int off = 1; off < 16; off <<= 1) {
                    ps += __shfl_xor(ps, off, 16);
                    pd += __shfl_xor(pd, off, 16);
                }
                if (lrow == 0) { as_nx[row] = ps; ad_nx[row] = pd; }
            }
        }
    }
}

// ---------------- launch ----------------

extern "C" void kernel_launch(void* const* d_in, const int* in_sizes, int n_in,
                              void* d_out, int out_size, void* d_ws, size_t ws_size,
                              hipStream_t stream) {
    const float* x     = (const float*)d_in[0];
    const int*   ei    = (const int*)d_in[1];
    const float* W_emb = (const float*)d_in[2];
    const float* b_emb = (const float*)d_in[3];
    const float* W1g   = (const float*)d_in[4];
    const float* as1g  = (const float*)d_in[5];
    const float* ad1g  = (const float*)d_in[6];
    const float* b1    = (const float*)d_in[7];
    const float* Wl[3]  = {(const float*)d_in[8],  (const float*)d_in[12], (const float*)d_in[16]};
    const float* asl[3] = {(const float*)d_in[9],  (const float*)d_in[13], (const float*)d_in[17]};
    const float* adl[3] = {(const float*)d_in[10], (const float*)d_in[14], (const float*)d_in[18]};
    const float* bl[3]  = {(const float*)d_in[11], (const float*)d_in[15], (const float*)d_in[19]};
    float* out = (float*)d_out;

    int N = in_sizes[0];
    int E = in_sizes[1] / 2;
    int Et = E + N;
    const int OVF_CAP = 65536;
    int nScat = (Et + 255) / 256;

    char* ws = (char*)d_ws;
    size_t off = 0;
    auto alloc = [&](size_t bytes) { size_t p = off; off += (bytes + 255) & ~(size_t)255; return p; };
    int*   deg      = (int*)(ws + alloc((size_t)(N + 1) * 4));   // deg[N] = ovf count
    int2*  ovf      = (int2*)(ws + alloc((size_t)OVF_CAP * 8));
    int*   csr_pad  = (int*)(ws + alloc((size_t)N * 64 * 4));
    float* consts   = (float*)(ws + alloc(272 * 4));
    float* a_s0     = (float*)(ws + alloc((size_t)N * 4));
    float* a_d0     = (float*)(ws + alloc((size_t)N * 4));
    float* a_s1     = (float*)(ws + alloc((size_t)N * 4));
    float* a_d1     = (float*)(ws + alloc((size_t)N * 4));
    float* hA       = (float*)(ws + alloc((size_t)N * 128 * 4));
    unsigned* aggp  = (unsigned*)(ws + alloc((size_t)N * 64 * 8));
    ushort* wt_hi[3]; ushort* wt_lo[3];
    float* was[3]; float* wad[3];
    for (int l = 0; l < 3; l++) {
        wt_hi[l] = (ushort*)(ws + alloc(128 * 128 * 2));
        wt_lo[l] = (ushort*)(ws + alloc(128 * 128 * 2));
        was[l]   = (float*)(ws + alloc(128 * 4));
        wad[l]   = (float*)(ws + alloc(128 * 4));
    }

    hipMemsetAsync(deg, 0, (size_t)(N + 1) * 4, stream);
    k_init<<<nScat + 196, 256, 0, stream>>>(ei, E, N, nScat, deg, csr_pad, ovf, OVF_CAP,
                                            Wl[0], Wl[1], Wl[2], asl[0], asl[1], asl[2],
                                            adl[0], adl[1], adl[2],
                                            W_emb, b_emb, W1g, as1g, ad1g,
                                            wt_hi[0], wt_lo[0], wt_hi[1], wt_lo[1],
                                            wt_hi[2], wt_lo[2],
                                            was[0], was[1], was[2], wad[0], wad[1], wad[2],
                                            consts);

    k_l1<<<(N + 3) / 4, 256, 0, stream>>>(x, deg, csr_pad, ovf, consts, b1,
                                          was[0], wad[0], hA, a_s0, a_d0, N);

    float* as_cur = a_s0; float* ad_cur = a_d0;
    float* as_nxt = a_s1; float* ad_nxt = a_d1;
    for (int l = 0; l < 3; l++) {
        k_aggh<<<(N + 3) / 4, 256, 0, stream>>>(hA, as_cur, ad_cur, deg, csr_pad,
                                                ovf, aggp, N);
        if (l < 2) {
            k_gemm<<<(N + 127) / 128, 512, 0, stream>>>((const uint2*)aggp, wt_hi[l], wt_lo[l], bl[l], hA,
                                                        was[l + 1], wad[l + 1], as_nxt, ad_nxt, N, 1);
            float* t;
            t = as_cur; as_cur = as_nxt; as_nxt = t;
            t = ad_cur; ad_cur = ad_nxt; ad_nxt = t;
        } else {
            k_gemm<<<(N + 127) / 128, 512, 0, stream>>>((const uint2*)aggp, wt_hi[l], wt_lo[l], bl[l], out,
                                                        nullptr, nullptr, nullptr, nullptr, N, 0);
        }
    }
}